// Round 13
// baseline (285.719 us; speedup 1.0000x reference)
//
#include <hip/hip_runtime.h>
#include <math.h>

#define B_ 256
#define G_ 4000
#define P_ 128
#define D_ 12000
#define H_ 64
#define O_ 16
#define GH_ 128
#define CH_ 8
#define C_ 5
#define K_ 3
#define EPS_ 1e-5f
#define KCH_ 500    // gate gemm1: K-chunk per tile
#define KIN_ 100    // gate gemm1: inner K tile in LDS
#define TILE_ 640   // expert gene tile (n_p ~ 400 fits in one pass)

// ---------------------------------------------------------------------------
// K1 (R5-proven): blocks [0,128) = per-pathway compaction (+ zero counters);
//                 blocks [128,384) = gate GEMM1 partial tiles -> hpart.
// ---------------------------------------------------------------------------
__global__ __launch_bounds__(512) void k_pre(const float* __restrict__ gene_mask,
                                             const float* __restrict__ x_rna,
                                             const float* __restrict__ gw1,
                                             int* __restrict__ cnt,
                                             int* __restrict__ gindex,
                                             int* __restrict__ cntr,
                                             float* __restrict__ hpart) {
  int t = threadIdx.x;

  if (blockIdx.x < P_) {
    int p = blockIdx.x;
    if (t < 2) cntr[p * 2 + t] = 0;          // zero the 256 sample counters
    int lane = t & 63;
    int w = t >> 6;
    __shared__ int wcnt[8];
    int* lp = gindex + (size_t)p * G_;
    const int per = (G_ + 7) / 8;   // 500
    int start = w * per;
    int end = start + per; if (end > G_) end = G_;

    int count = 0;
    for (int g0 = start; g0 < end; g0 += 64) {
      int g = g0 + lane;
      bool act = (g < end) && (gene_mask[(size_t)g * P_ + p] != 0.0f);
      count += __popcll(__ballot(act));
    }
    if (lane == 0) wcnt[w] = count;
    __syncthreads();
    if (t == 0) {
      int tot = 0;
      for (int i = 0; i < 8; ++i) tot += wcnt[i];
      cnt[p] = tot;
    }
    int base = 0;
    for (int i = 0; i < w; ++i) base += wcnt[i];
    for (int g0 = start; g0 < end; g0 += 64) {
      int g = g0 + lane;
      bool act = (g < end) && (gene_mask[(size_t)g * P_ + p] != 0.0f);
      unsigned long long bal = __ballot(act);
      int rank = __popcll(bal & ((1ull << lane) - 1ull));
      if (act) lp[base + rank] = g;
      base += __popcll(bal);
    }
    return;
  }

  // ---- gate GEMM1 partial tile ----
  int idx = blockIdx.x - P_;        // 0..255
  int bt = idx >> 5;                // 8 b-tiles of 32
  int sub = idx & 31;
  int jt = sub >> 3;                // 4 j-tiles of 32
  int kc = sub & 7;                 // 8 k-chunks of 500
  int b0 = bt * 32;
  int j0 = jt * 32;

  __shared__ float xa[32 * KIN_];
  __shared__ float wa[KIN_ * 32];
  float2* wa2 = (float2*)wa;

  int bi = t >> 4;
  int jp = t & 15;
  float2 acc = {0.f, 0.f};

  for (int ch = 0; ch < KCH_ / KIN_; ++ch) {
    int kb = kc * KCH_ + ch * KIN_;
    __syncthreads();
    for (int id = t; id < 32 * KIN_; id += 512) {
      int r = id / KIN_, c = id - r * KIN_;
      xa[id] = x_rna[(size_t)(b0 + r) * G_ + kb + c];
    }
    for (int id = t; id < KIN_ * 32; id += 512) {
      int r = id >> 5, c = id & 31;
      wa[id] = gw1[(size_t)(kb + r) * GH_ + j0 + c];
    }
    __syncthreads();
#pragma unroll 4
    for (int kk = 0; kk < KIN_; ++kk) {
      float x = xa[bi * KIN_ + kk];
      float2 w = wa2[kk * 16 + jp];
      acc.x = fmaf(x, w.x, acc.x);
      acc.y = fmaf(x, w.y, acc.y);
    }
  }
  float2* out = (float2*)(hpart + ((size_t)kc * B_ + (b0 + bi)) * GH_ + j0 + jp * 2);
  *out = acc;
}

// ---------------------------------------------------------------------------
// K2: fully fused gate + expert + finish. 768 blocks = (sample b, slot k).
// Each block: (1) recompute sample-b gate (combine+GEMM2+top3; identical
// across the 3 blocks of b — 16K MACs, trivial); k==0 writes out_gw.
// (2) R5-proven fp32 float4 expert for pathway s_idx[k] -> BN -> ReLU -> W2,
// scaled by sigmoid weight -> contrib[bk][16] (agent-scope stores).
// (3) last-arriving block of each sample (device atomic counter) sums the 3
// contributions and runs the classifier. Deterministic: the final value is
// an order-independent sum; counters re-zeroed by K1 every launch.
// ---------------------------------------------------------------------------
__global__ __launch_bounds__(512) void k_fused(const float* __restrict__ xr,
                                               const float* __restrict__ xc,
                                               const float* __restrict__ xm,
                                               const float* __restrict__ hpart,
                                               const float* __restrict__ gb1,
                                               const float* __restrict__ gw2,
                                               const float* __restrict__ gb2,
                                               const float* __restrict__ W1,
                                               const float* __restrict__ b1,
                                               const float* __restrict__ bn_g,
                                               const float* __restrict__ bn_b,
                                               const float* __restrict__ bn_m,
                                               const float* __restrict__ bn_v,
                                               const float* __restrict__ W2,
                                               const float* __restrict__ b2,
                                               const float* __restrict__ cw1,
                                               const float* __restrict__ cb1,
                                               const float* __restrict__ cw2,
                                               const float* __restrict__ cb2,
                                               const int* __restrict__ cnt,
                                               const int* __restrict__ gindex,
                                               float* __restrict__ out_gw,
                                               float* __restrict__ contrib,
                                               int* __restrict__ cntr,
                                               float* __restrict__ out_logits) {
  int bk = blockIdx.x;              // 768
  int b = bk / K_;
  int k = bk - b * K_;
  int t = threadIdx.x;

  __shared__ float hid[GH_];
  __shared__ float logitS[P_];
  __shared__ int   s_idx[K_];
  __shared__ float s_val[K_];
  __shared__ int   glist[TILE_];
  __shared__ float xv0[TILE_], xv1[TILE_], xv2[TILE_];
  __shared__ float part[32][H_];
  __shared__ float hs[H_];
  __shared__ float fs[O_];
  __shared__ float chS[CH_];
  __shared__ int   oldS;

  // ---- (1) gate for sample b (redundant x3, identical results) ----
  if (t < GH_) {
    float s = gb1[t];
    for (int kc = 0; kc < 8; ++kc)
      s += hpart[((size_t)kc * B_ + b) * GH_ + t];
    hid[t] = fmaxf(s, 0.f);
  }
  __syncthreads();

  if (t < P_) {
    float acc = gb2[t];
    for (int jj = 0; jj < GH_; ++jj)
      acc = fmaf(hid[jj], gw2[(size_t)jj * P_ + t], acc);
    logitS[t] = acc;
  }
  __syncthreads();

  if (t < 64) {
    float v0 = logitS[t], v1 = logitS[t + 64];
    int i0 = t, i1 = t + 64;
    for (int kk = 0; kk < K_; ++kk) {
      float v; int i;
      if (v0 > v1 || (v0 == v1 && i0 < i1)) { v = v0; i = i0; }
      else                                  { v = v1; i = i1; }
      for (int sft = 1; sft < 64; sft <<= 1) {
        float ov = __shfl_xor(v, sft);
        int   oi = __shfl_xor(i, sft);
        if (ov > v || (ov == v && oi < i)) { v = ov; i = oi; }
      }
      if (t == 0) {
        s_idx[kk] = i;
        s_val[kk] = 1.f / (1.f + expf(-v));
      }
      if (i0 == i) v0 = -INFINITY;
      if (i1 == i) v1 = -INFINITY;
    }
  }
  __syncthreads();

  if (k == 0 && t < P_) {
    float gwv = 0.f;
    for (int kk = 0; kk < K_; ++kk) if (s_idx[kk] == t) gwv = s_val[kk];
    out_gw[(size_t)b * P_ + t] = gwv;
  }

  int p = s_idx[k];
  float wgt = s_val[k];

  // ---- (2) expert: R5 fp32 float4 structure ----
  int w = t >> 6;                   // wave 0..7
  int lane = t & 63;
  int j4 = lane >> 4;               // gene subgroup 0..3
  int hq = lane & 15;               // h-quad
  int n = cnt[p];
  const int* gp = gindex + (size_t)p * G_;
  const float* W1p = W1 + (size_t)p * D_ * H_;
  const float* xrb = xr + (size_t)b * G_;
  const float* xcb = xc + (size_t)b * G_;
  const float* xmb = xm + (size_t)b * G_;

  float a0 = 0.f, a1 = 0.f, a2 = 0.f, a3 = 0.f;

  for (int t0 = 0; t0 < n; t0 += TILE_) {
    int m = n - t0; if (m > TILE_) m = TILE_;
    __syncthreads();
    for (int i = t; i < m; i += 512) {
      int g = gp[t0 + i];
      glist[i] = g;
      xv0[i] = xrb[g]; xv1[i] = xcb[g]; xv2[i] = xmb[g];
    }
    __syncthreads();
    for (int i0 = w * 4 + j4; i0 < m; i0 += 32) {
      int g = glist[i0];
      float x0 = xv0[i0], x1 = xv1[i0], x2 = xv2[i0];
      const float* r = W1p + (size_t)g * H_ + hq * 4;
      float4 w0 = *(const float4*)r;
      float4 w1 = *(const float4*)(r + (size_t)G_ * H_);
      float4 w2 = *(const float4*)(r + (size_t)(2 * G_) * H_);
      a0 = fmaf(x0, w0.x, a0); a1 = fmaf(x0, w0.y, a1);
      a2 = fmaf(x0, w0.z, a2); a3 = fmaf(x0, w0.w, a3);
      a0 = fmaf(x1, w1.x, a0); a1 = fmaf(x1, w1.y, a1);
      a2 = fmaf(x1, w1.z, a2); a3 = fmaf(x1, w1.w, a3);
      a0 = fmaf(x2, w2.x, a0); a1 = fmaf(x2, w2.y, a1);
      a2 = fmaf(x2, w2.z, a2); a3 = fmaf(x2, w2.w, a3);
    }
  }
  {
    float4 av = {a0, a1, a2, a3};
    *(float4*)&part[w * 4 + j4][hq * 4] = av;
  }
  __syncthreads();

  if (t < H_) {
    float s = 0.f;
#pragma unroll
    for (int ss = 0; ss < 32; ++ss) s += part[ss][t];
    int ph = p * H_ + t;
    s += b1[ph];
    float hn = (s - bn_m[ph]) * (bn_g[ph] * rsqrtf(bn_v[ph] + EPS_)) + bn_b[ph];
    hs[t] = fmaxf(hn, 0.f);
  }
  __syncthreads();

  if (t < O_) {
    const float* W2p = W2 + (size_t)p * H_ * O_;
    float o = b2[p * O_ + t];
    for (int jj = 0; jj < H_; ++jj) o = fmaf(hs[jj], W2p[jj * O_ + t], o);
    __hip_atomic_store(&contrib[(size_t)bk * O_ + t], wgt * o,
                       __ATOMIC_RELEASE, __HIP_MEMORY_SCOPE_AGENT);
  }
  __threadfence();
  __syncthreads();

  // ---- (3) last block of sample b finishes ----
  if (t == 0)
    oldS = __hip_atomic_fetch_add(&cntr[b], 1, __ATOMIC_ACQ_REL,
                                  __HIP_MEMORY_SCOPE_AGENT);
  __syncthreads();
  if (oldS != K_ - 1) return;
  __threadfence();

  if (t < O_) {
    float f = 0.f;
#pragma unroll
    for (int kk = 0; kk < K_; ++kk)
      f += __hip_atomic_load(&contrib[(size_t)(b * K_ + kk) * O_ + t],
                             __ATOMIC_ACQUIRE, __HIP_MEMORY_SCOPE_AGENT);
    fs[t] = f;
  }
  __syncthreads();

  if (t < CH_) {
    float a = cb1[t];
    for (int o = 0; o < O_; ++o) a = fmaf(fs[o], cw1[o * CH_ + t], a);
    chS[t] = fmaxf(a, 0.f);
  }
  __syncthreads();

  if (t < C_) {
    float a = cb2[t];
    for (int jj = 0; jj < CH_; ++jj) a = fmaf(chS[jj], cw2[jj * C_ + t], a);
    out_logits[(size_t)b * C_ + t] = a;
  }
}

// ---------------------------------------------------------------------------
extern "C" void kernel_launch(void* const* d_in, const int* in_sizes, int n_in,
                              void* d_out, int out_size, void* d_ws, size_t ws_size,
                              hipStream_t stream) {
  const float* x_rna    = (const float*)d_in[0];
  const float* x_cnv    = (const float*)d_in[1];
  const float* x_met    = (const float*)d_in[2];
  const float* gene_mask= (const float*)d_in[3];
  const float* gate_w1  = (const float*)d_in[4];
  const float* gate_b1  = (const float*)d_in[5];
  const float* gate_w2  = (const float*)d_in[6];
  const float* gate_b2  = (const float*)d_in[7];
  const float* W1       = (const float*)d_in[8];
  const float* b1       = (const float*)d_in[9];
  const float* bn_g     = (const float*)d_in[10];
  const float* bn_b     = (const float*)d_in[11];
  const float* bn_m     = (const float*)d_in[12];
  const float* bn_v     = (const float*)d_in[13];
  const float* W2       = (const float*)d_in[14];
  const float* b2       = (const float*)d_in[15];
  const float* cls_w1   = (const float*)d_in[16];
  const float* cls_b1   = (const float*)d_in[17];
  const float* cls_w2   = (const float*)d_in[18];
  const float* cls_b2   = (const float*)d_in[19];

  float* out_logits = (float*)d_out;                   // [B, C]
  float* out_gw     = (float*)d_out + (size_t)B_ * C_; // [B, P]

  // workspace layout (bytes)
  char* ws = (char*)d_ws;
  int*   cnt     = (int*)(ws + 0);                 // 512
  int*   gindex  = (int*)(ws + 512);               // 2,048,000
  int*   cntr    = (int*)(ws + 2048512);           // 1024
  float* contrib = (float*)(ws + 2049536);         // 768*16*4 = 49,152
  float* hpart   = (float*)(ws + 2098688);         // 1,048,576

  hipLaunchKernelGGL(k_pre, dim3(P_ + 256), dim3(512), 0, stream,
                     gene_mask, x_rna, gate_w1, cnt, gindex, cntr, hpart);
  hipLaunchKernelGGL(k_fused, dim3(B_ * K_), dim3(512), 0, stream,
                     x_rna, x_cnv, x_met, hpart, gate_b1, gate_w2, gate_b2,
                     W1, b1, bn_g, bn_b, bn_m, bn_v, W2, b2,
                     cls_w1, cls_b1, cls_w2, cls_b2,
                     cnt, gindex, out_gw, contrib, cntr, out_logits);
}